// Round 4
// baseline (416.830 us; speedup 1.0000x reference)
//
#include <hip/hip_runtime.h>

typedef __bf16 bf16;
typedef bf16 bf16x8 __attribute__((ext_vector_type(8)));
typedef float f32x4 __attribute__((ext_vector_type(4)));

#define MFMA(a, b, c) __builtin_amdgcn_mfma_f32_16x16x32_bf16((a), (b), (c), 0, 0, 0)

// N=32, BSZ=512, NE=7, DIN=512, DH=256 ; M = N*BSZ*NE = 114688 rows
// Frag layouts (16x16x32 bf16, HW-verified): A: lane l -> A[m=l&15][k=(l>>4)*8+j]
// B: lane l -> B[k=(l>>4)*8+j][n=l&15] ; C/D: col=l&15, row=(l>>4)*4+reg.

// ---------------------------------------------------------------------------
// blocks 0..95: pack W0 -> B-frag order W0B[((nt*16+ks)*64+l)*8+j], same W1B
// blocks 96..607: relation MLP + pairwise pre-sum bsum[b][128]
// ---------------------------------------------------------------------------
__global__ __launch_bounds__(256) void k_prep_bsum(
    const float* __restrict__ W0, const float* __restrict__ W1,
    bf16* __restrict__ W0B, bf16* __restrict__ W1B,
    const float* __restrict__ ctx, const float* __restrict__ R0,
    const float* __restrict__ r0, const float* __restrict__ R1,
    const float* __restrict__ r1, float* __restrict__ bsum) {
  if (blockIdx.x < 96) {
    int g = blockIdx.x * 256 + threadIdx.x;
    if (g < 16384) {                        // W0B: nt(16) x ks(16) x lane(64)
      int l = g & 63;
      int n = ((g >> 10) << 4) + (l & 15);
      int kb = (((g >> 6) & 15) << 5) + ((l >> 4) << 3);
      bf16x8 v;
#pragma unroll
      for (int j = 0; j < 8; ++j) v[j] = (bf16)W0[(kb + j) * 256 + n];
      *(bf16x8*)&W0B[g * 8] = v;
    } else {                                // W1B: nt(16) x ks(8) x lane(64)
      int h = g - 16384;
      int l = h & 63;
      int n = ((h >> 9) << 4) + (l & 15);
      int kb = (((h >> 6) & 7) << 5) + ((l >> 4) << 3);
      bf16x8 v;
#pragma unroll
      for (int j = 0; j < 8; ++j) v[j] = (bf16)W1[(kb + j) * 256 + n];
      *(bf16x8*)&W1B[h * 8] = v;
    }
  } else {
    __shared__ float ctx_l[105], R0_l[320], r0_l[64], R1_l[192], r1_l[3];
    __shared__ float h2[21 * 65];
    __shared__ float bp[63];
    const int t = threadIdx.x;
    const int b = blockIdx.x - 96;
    if (t < 105) ctx_l[t] = ctx[b * 105 + t];
    if (t < 64) r0_l[t] = r0[t];
    if (t < 192) R1_l[t] = R1[t];
    if (t < 3) r1_l[t] = r1[t];
    for (int i = t; i < 320; i += 256) R0_l[i] = R0[i];
    __syncthreads();
    for (int idx = t; idx < 1344; idx += 256) {
      int p = idx >> 6, u = idx & 63;
      float a = r0_l[u];
#pragma unroll
      for (int x = 0; x < 5; ++x) a += ctx_l[p * 5 + x] * R0_l[x * 64 + u];
      h2[p * 65 + u] = fmaxf(a, 0.f);
    }
    __syncthreads();
    if (t < 63) {
      int p = t / 3, y = t - p * 3;
      float a = r1_l[y];
      for (int u = 0; u < 64; ++u) a += h2[p * 65 + u] * R1_l[u * 3 + y];
      bp[t] = a;
    }
    __syncthreads();
    if (t < 128) {
      float a = 0.f;
      int pi = 0;
#pragma unroll
      for (int i = 0; i < 7; ++i)
#pragma unroll
        for (int j = i + 1; j < 7; ++j) {
          int bi = (t >> (6 - i)) & 1, bj = (t >> (6 - j)) & 1;
          a += bp[pi * 3 + bi + bj];
          ++pi;
        }
      bsum[b * 128 + t] = a;
    }
  }
}

// ---------------------------------------------------------------------------
// Pass A: h0 = relu(X @ W0 + b0). Tile 128m x 128n, grid 896x2, 256 thr.
// m97 shape: all MFMA operands via ds_read_b128; staging prefetched one full
// iter ahead into regs; one barrier/iter. fp32->bf16 cvt fused in A-frag read.
// LDS 53248 B -> 3 blocks/CU.
// ---------------------------------------------------------------------------
__global__ __launch_bounds__(256, 3) void k_l0(const float* __restrict__ X,
                                               const bf16* __restrict__ W0B,
                                               const float* __restrict__ b0,
                                               bf16* __restrict__ h0) {
  __shared__ __align__(16) float xs[2][128 * 36];    // 36864 B (pad 32->36)
  __shared__ __align__(16) bf16 wsb[2][8 * 64 * 8];  // 16384 B
  const int tid = threadIdx.x;
  const int w = tid >> 6, lane = tid & 63, l16 = lane & 15, quad = lane >> 4;
  const int mb = blockIdx.x >> 1, nb = blockIdx.x & 1;
  const int mt0 = (w >> 1) * 4;        // wave m-tile base (of 8)
  const int nt0 = (w & 1) * 4;         // wave n-tile base (of 8 local)

  const int xr = tid >> 1, xh = tid & 1;             // X stage: row, 16-f half
  const float* xg = X + (long)(mb * 128 + xr) * 512 + xh * 16;
  const int ws0 = tid * 2;                           // W stage: slot pair
  const int wnt = ws0 >> 6, wl = ws0 & 63;

  f32x4 acc[4][4];
#pragma unroll
  for (int i = 0; i < 4; ++i)
#pragma unroll
    for (int j = 0; j < 4; ++j) acc[i][j] = (f32x4){0.f, 0.f, 0.f, 0.f};

  // prologue: stage it=0
  float4 xv0 = ((const float4*)xg)[0], xv1 = ((const float4*)xg)[1];
  float4 xv2 = ((const float4*)xg)[2], xv3 = ((const float4*)xg)[3];
  int4 wv0 = *(const int4*)&W0B[(((nb * 8 + wnt) * 16) * 64 + wl) * 8];
  int4 wv1 = *(const int4*)&W0B[(((nb * 8 + wnt) * 16) * 64 + wl + 1) * 8];
  {
    float* xd = &xs[0][xr * 36 + xh * 16];
    *(float4*)xd = xv0; *(float4*)(xd + 4) = xv1;
    *(float4*)(xd + 8) = xv2; *(float4*)(xd + 12) = xv3;
    *(int4*)&wsb[0][ws0 * 8] = wv0; *(int4*)&wsb[0][(ws0 + 1) * 8] = wv1;
  }
  __syncthreads();

  for (int it = 0; it < 16; ++it) {
    const int cur = it & 1;
    if (it < 15) {                      // prefetch it+1 (latency under compute)
      const float* xp = xg + (it + 1) * 32;
      xv0 = ((const float4*)xp)[0]; xv1 = ((const float4*)xp)[1];
      xv2 = ((const float4*)xp)[2]; xv3 = ((const float4*)xp)[3];
      wv0 = *(const int4*)&W0B[(((nb * 8 + wnt) * 16 + it + 1) * 64 + wl) * 8];
      wv1 = *(const int4*)&W0B[(((nb * 8 + wnt) * 16 + it + 1) * 64 + wl + 1) * 8];
    }
    bf16x8 af[4], bf[4];
#pragma unroll
    for (int mt = 0; mt < 4; ++mt) {    // A-frag: fp32 LDS -> cvt bf16
      const float* ap = &xs[cur][((mt0 + mt) * 16 + l16) * 36 + quad * 8];
      f32x4 a0 = *(const f32x4*)ap;
      f32x4 a1 = *(const f32x4*)(ap + 4);
      bf16x8 t;
      t[0] = (bf16)a0[0]; t[1] = (bf16)a0[1]; t[2] = (bf16)a0[2]; t[3] = (bf16)a0[3];
      t[4] = (bf16)a1[0]; t[5] = (bf16)a1[1]; t[6] = (bf16)a1[2]; t[7] = (bf16)a1[3];
      af[mt] = t;
    }
#pragma unroll
    for (int nt = 0; nt < 4; ++nt)
      bf[nt] = *(const bf16x8*)&wsb[cur][((nt0 + nt) * 64 + lane) * 8];
#pragma unroll
    for (int mt = 0; mt < 4; ++mt)
#pragma unroll
      for (int nt = 0; nt < 4; ++nt) acc[mt][nt] = MFMA(af[mt], bf[nt], acc[mt][nt]);
    if (it < 15) {                      // write prefetched tile -> other buffer
      float* xd = &xs[cur ^ 1][xr * 36 + xh * 16];
      *(float4*)xd = xv0; *(float4*)(xd + 4) = xv1;
      *(float4*)(xd + 8) = xv2; *(float4*)(xd + 12) = xv3;
      *(int4*)&wsb[cur ^ 1][ws0 * 8] = wv0; *(int4*)&wsb[cur ^ 1][(ws0 + 1) * 8] = wv1;
      __syncthreads();
    }
  }

  // epilogue: bias+relu+cvt -> LDS transpose (reuse xs) -> coalesced stores
  float bb[4];
#pragma unroll
  for (int nt = 0; nt < 4; ++nt) bb[nt] = b0[nb * 128 + (nt0 + nt) * 16 + l16];
  __syncthreads();
  bf16* hs = (bf16*)&xs[0][0];         // 128 x 136 (stride 272 B, 16-aligned)
#pragma unroll
  for (int mt = 0; mt < 4; ++mt)
#pragma unroll
    for (int nt = 0; nt < 4; ++nt)
#pragma unroll
      for (int r = 0; r < 4; ++r)
        hs[((mt0 + mt) * 16 + quad * 4 + r) * 136 + (nt0 + nt) * 16 + l16] =
            (bf16)fmaxf(acc[mt][nt][r] + bb[nt], 0.f);
  __syncthreads();
  const long gb = (long)(mb * 128 + xr) * 256 + nb * 128 + xh * 64;
  const bf16* hr = &hs[xr * 136 + xh * 64];
#pragma unroll
  for (int c = 0; c < 8; ++c)
    *(int4*)&h0[gb + c * 8] = *(const int4*)&hr[c * 8];
}

// ---------------------------------------------------------------------------
// Pass B: un = relu(h0@W1+b1) @ W2 + b2, layer-2 fused in-register.
// Tile 128m x 256n (all 16 n-tiles), 512 thr / 8 waves, grid 896.
// wave (wr,wc): m-tiles wr*2..+2, n-tiles wc*8..+8; acc 2x8.
// ---------------------------------------------------------------------------
__global__ __launch_bounds__(512, 4) void k_l12(const bf16* __restrict__ h0,
                                                const bf16* __restrict__ W1B,
                                                const float* __restrict__ b1,
                                                const float* __restrict__ W2,
                                                const float* __restrict__ b2,
                                                float* __restrict__ un) {
  __shared__ __align__(16) bf16 as2[2][128 * 40];    // 20480 B (pad 32->40)
  __shared__ __align__(16) bf16 wsb[2][16 * 64 * 8]; // 32768 B
  __shared__ float b1s[256];
  __shared__ float w2s[512];
  __shared__ float parts[2][128][2];
  const int tid = threadIdx.x;
  const int w = tid >> 6, lane = tid & 63, l16 = lane & 15, quad = lane >> 4;
  const int mb = blockIdx.x;
  const int mt0 = (w >> 1) * 2;
  const int ntq = (w & 1) * 8;
  if (tid < 256) b1s[tid] = b1[tid];
  w2s[tid] = W2[tid & 511];

  const int ar = tid >> 2, aq = tid & 3;
  const bf16* ag = h0 + (long)(mb * 128 + ar) * 256 + aq * 8;
  const int ws0 = tid * 2;
  const int wnt = ws0 >> 6, wl = ws0 & 63;

  f32x4 acc[2][8];
#pragma unroll
  for (int i = 0; i < 2; ++i)
#pragma unroll
    for (int j = 0; j < 8; ++j) acc[i][j] = (f32x4){0.f, 0.f, 0.f, 0.f};

  int4 av = *(const int4*)ag;
  int4 wv0 = *(const int4*)&W1B[((wnt * 8) * 64 + wl) * 8];
  int4 wv1 = *(const int4*)&W1B[((wnt * 8) * 64 + wl + 1) * 8];
  *(int4*)&as2[0][ar * 40 + aq * 8] = av;
  *(int4*)&wsb[0][ws0 * 8] = wv0; *(int4*)&wsb[0][(ws0 + 1) * 8] = wv1;
  __syncthreads();

  for (int it = 0; it < 8; ++it) {
    const int cur = it & 1;
    if (it < 7) {
      av = *(const int4*)(ag + (it + 1) * 32);
      wv0 = *(const int4*)&W1B[((wnt * 8 + it + 1) * 64 + wl) * 8];
      wv1 = *(const int4*)&W1B[((wnt * 8 + it + 1) * 64 + wl + 1) * 8];
    }
    bf16x8 af[2];
#pragma unroll
    for (int mt = 0; mt < 2; ++mt)
      af[mt] = *(const bf16x8*)&as2[cur][((mt0 + mt) * 16 + l16) * 40 + quad * 8];
#pragma unroll
    for (int h = 0; h < 2; ++h) {
      bf16x8 bf[4];
#pragma unroll
      for (int nt = 0; nt < 4; ++nt)
        bf[nt] = *(const bf16x8*)&wsb[cur][((ntq + h * 4 + nt) * 64 + lane) * 8];
#pragma unroll
      for (int mt = 0; mt < 2; ++mt)
#pragma unroll
        for (int nt = 0; nt < 4; ++nt)
          acc[mt][h * 4 + nt] = MFMA(af[mt], bf[nt], acc[mt][h * 4 + nt]);
    }
    if (it < 7) {
      *(int4*)&as2[cur ^ 1][ar * 40 + aq * 8] = av;
      *(int4*)&wsb[cur ^ 1][ws0 * 8] = wv0; *(int4*)&wsb[cur ^ 1][(ws0 + 1) * 8] = wv1;
      __syncthreads();
    }
  }

  // epilogue: h1=relu(acc+b1) (fp32), partial un = sum_n h1*W2, 16-lane reduce
  float sv[16];
#pragma unroll
  for (int i = 0; i < 16; ++i) sv[i] = 0.f;
#pragma unroll
  for (int nt = 0; nt < 8; ++nt) {
    const int n = (ntq + nt) * 16 + l16;
    const float bias = b1s[n];
    const float w2a = w2s[n * 2], w2b = w2s[n * 2 + 1];
#pragma unroll
    for (int mt = 0; mt < 2; ++mt)
#pragma unroll
      for (int r = 0; r < 4; ++r) {
        const float h1 = fmaxf(acc[mt][nt][r] + bias, 0.f);
        sv[(mt * 4 + r) * 2 + 0] += h1 * w2a;
        sv[(mt * 4 + r) * 2 + 1] += h1 * w2b;
      }
  }
#pragma unroll
  for (int i = 0; i < 16; ++i)
#pragma unroll
    for (int o = 1; o < 16; o <<= 1) sv[i] += __shfl_xor(sv[i], o, 64);
  if (l16 == 0) {
#pragma unroll
    for (int mt = 0; mt < 2; ++mt)
#pragma unroll
      for (int r = 0; r < 4; ++r)
#pragma unroll
        for (int c = 0; c < 2; ++c)
          parts[w & 1][(mt0 + mt) * 16 + quad * 4 + r][c] = sv[(mt * 4 + r) * 2 + c];
  }
  __syncthreads();
  if (tid < 256) {
    const int m = tid >> 1, c = tid & 1;
    un[(long)(mb * 128 + m) * 2 + c] = parts[0][m][c] + parts[1][m][c] + b2[c];
  }
}

// ---------------------------------------------------------------------------
// joint + marginals: one wave per (n,b) row, no barriers/LDS (unchanged, R3).
// ---------------------------------------------------------------------------
__global__ __launch_bounds__(256) void k_joint(const float* __restrict__ un,
                                               const float* __restrict__ bsum,
                                               float* __restrict__ out_marg,
                                               float* __restrict__ out_joint) {
  const int lane = threadIdx.x & 63;
  const int wave = threadIdx.x >> 6;
  const int gw = blockIdx.x * 4 + wave;
  const int b = gw & 511;
  const long row = gw;
  const int urow = __builtin_amdgcn_readfirstlane(gw);
  float u[14];
#pragma unroll
  for (int i = 0; i < 14; ++i) u[i] = un[(long)urow * 14 + i];
  const float bs0 = bsum[b * 128 + lane];
  const float bs1 = bsum[b * 128 + 64 + lane];
  float jc = 0.f;
#pragma unroll
  for (int i = 1; i < 7; ++i) jc += u[i * 2 + ((lane >> (6 - i)) & 1)];
  const float j0 = bs0 + jc + u[0];
  const float j1 = bs1 + jc + u[1];
  float m = fmaxf(j0, j1);
#pragma unroll
  for (int o = 1; o < 64; o <<= 1) m = fmaxf(m, __shfl_xor(m, o, 64));
  const float e0 = __expf(j0 - m), e1 = __expf(j1 - m);
  float t = e0 + e1;
  float s1e = e1;
  float uu[6];
#pragma unroll
  for (int q = 0; q < 6; ++q) {
    float pt = __shfl_xor(t, 1 << q, 64);
    uu[q] = ((lane >> q) & 1) ? t : pt;
    t += pt;
    s1e += __shfl_xor(s1e, 1 << q, 64);
#pragma unroll
    for (int jq = 0; jq < q; ++jq) uu[jq] += __shfl_xor(uu[jq], 1 << q, 64);
  }
  const float lZ = m + __logf(t);
  out_joint[row * 128 + lane] = j0 - lZ;
  out_joint[row * 128 + 64 + lane] = j1 - lZ;
  if (lane < 7) {
    const float s1 = (lane == 0) ? s1e : uu[6 - lane];
    out_marg[row * 7 + lane] = __logf(s1) - __logf(t - s1);
  }
}

// ---------------------------------------------------------------------------
extern "C" void kernel_launch(void* const* d_in, const int* in_sizes, int n_in,
                              void* d_out, int out_size, void* d_ws, size_t ws_size,
                              hipStream_t stream) {
  const float* input = (const float*)d_in[0];
  const float* ctx   = (const float*)d_in[1];
  // d_in[2]=lang_input, d_in[3]=num_markables: unused by the reference
  const float* W0 = (const float*)d_in[4];
  const float* b0 = (const float*)d_in[5];
  const float* W1 = (const float*)d_in[6];
  const float* b1 = (const float*)d_in[7];
  const float* W2 = (const float*)d_in[8];
  const float* b2 = (const float*)d_in[9];
  const float* R0 = (const float*)d_in[10];
  const float* r0 = (const float*)d_in[11];
  const float* R1 = (const float*)d_in[12];
  const float* r1 = (const float*)d_in[13];

  char* ws = (char*)d_ws;
  bf16* W0B = (bf16*)(ws + 0);           //   262144 B
  bf16* W1B = (bf16*)(ws + 262144);      //   131072 B
  bf16* h0  = (bf16*)(ws + 393216);      // 58720256 B
  float* un  = (float*)(ws + 59113472);  //   917504 B
  float* bsm = (float*)(ws + 60030976);  //   262144 B

  float* out_marg = (float*)d_out;
  float* out_joint = out_marg + 114688;

  hipLaunchKernelGGL(k_prep_bsum, dim3(608), dim3(256), 0, stream,
                     W0, W1, W0B, W1B, ctx, R0, r0, R1, r1, bsm);
  hipLaunchKernelGGL(k_l0, dim3(1792), dim3(256), 0, stream, input, W0B, b0, h0);
  hipLaunchKernelGGL(k_l12, dim3(896), dim3(512), 0, stream, h0, W1B, b1, W2, b2, un);
  hipLaunchKernelGGL(k_joint, dim3(4096), dim3(256), 0, stream, un, bsm, out_marg, out_joint);
}